// Round 5
// baseline (135.000 us; speedup 1.0000x reference)
//
#include <hip/hip_runtime.h>
#include <math.h>

// TransformDomainInterpolator — DUAL packed-real FFTs per wave (register ILP).
//
// Evidence (R0/R1/R4): time is per-wave-critical-path bound — halving total
// FFT work at halved occupancy changed nothing.  So: two independent packed
// FFTs per THREAD (batches 2g and 2g+1), interleaved in registers through the
// SAME verified 7-phase radix-8 pipeline.  One sincos per phase serves both
// chains; chain B's compute hides chain A's ds_read latency intra-wave;
// 7 barriers serve 2 batches.  F4 + epilogue LDS access via float4
// (pada keeps even/odd index pairs contiguous).
//
// Packing identity (HW-verified R4, absmax 0.015625):
//   z = x_r0 + i*x_r1,  W = IDFT(t * DFT(z)) / 1,  t_k = sgn*e^{i pi k/2048}:
//   odd0[n] = Re W[n] + (-1)^n*(S0_i - S1_r)/2048
//   odd1[n] = Im W[n] + (-1)^n*(S0_r + S1_i)/2048,  S^s = Sum_m (-1)^m x^s[m]
// even[m] = in_r passthrough (exact); lerp w = [0,0, 0/9..8/9, 1,1,1].
//
// Block = 256 thr = 2 batches; grid = batch/2 = 256 (1 block/CU, 35 KB LDS).

#define NSC  4096
#define PI_F 3.14159265358979323846f
#define RSQ2 0.70710678118654752f

__device__ __forceinline__ int pada(int i) { return i + 2 * (i >> 5); }

__device__ __forceinline__ void bf_fwd(float2& a, float2& c, float tc, float ts) {
  const float tx = a.x - c.x, ty = a.y - c.y;
  a.x += c.x; a.y += c.y;
  c.x = tx * tc - ty * ts;
  c.y = tx * ts + ty * tc;
}
__device__ __forceinline__ void bf_inv(float2& a, float2& c, float tc, float ts) {
  const float tx = c.x * tc - c.y * ts, ty = c.x * ts + c.y * tc;
  c.x = a.x - tx; c.y = a.y - ty;
  a.x += tx; a.y += ty;
}

__device__ __forceinline__ void fwd3(float2* x, float c, float s) {
  bf_fwd(x[0], x[4], c, -s);
  { const float cj = RSQ2 * (c - s), sj = RSQ2 * (c + s);
    bf_fwd(x[1], x[5], cj, -sj); }
  bf_fwd(x[2], x[6], -s, -c);
  { const float cj = -RSQ2 * (s + c), sj = RSQ2 * (c - s);
    bf_fwd(x[3], x[7], cj, -sj); }
  const float c2 = c * c - s * s, s2 = 2.f * c * s;
  bf_fwd(x[0], x[2], c2, -s2);  bf_fwd(x[4], x[6], c2, -s2);
  bf_fwd(x[1], x[3], -s2, -c2); bf_fwd(x[5], x[7], -s2, -c2);
  const float c4 = c2 * c2 - s2 * s2, s4 = 2.f * c2 * s2;
  bf_fwd(x[0], x[1], c4, -s4); bf_fwd(x[2], x[3], c4, -s4);
  bf_fwd(x[4], x[5], c4, -s4); bf_fwd(x[6], x[7], c4, -s4);
}

__device__ __forceinline__ void inv3(float2* x, float c, float s) {
  const float c2 = c * c - s * s, s2 = 2.f * c * s;
  const float c4 = c2 * c2 - s2 * s2, s4 = 2.f * c2 * s2;
  bf_inv(x[0], x[1], c4, s4); bf_inv(x[2], x[3], c4, s4);
  bf_inv(x[4], x[5], c4, s4); bf_inv(x[6], x[7], c4, s4);
  bf_inv(x[0], x[2], c2, s2);  bf_inv(x[4], x[6], c2, s2);
  bf_inv(x[1], x[3], -s2, c2); bf_inv(x[5], x[7], -s2, c2);
  bf_inv(x[0], x[4], c, s);
  { const float cj = RSQ2 * (c - s), sj = RSQ2 * (c + s);
    bf_inv(x[1], x[5], cj, sj); }
  bf_inv(x[2], x[6], -s, c);
  { const float cj = -RSQ2 * (s + c), sj = RSQ2 * (c - s);
    bf_inv(x[3], x[7], cj, sj); }
}

// F4 middle: fwd stages 1,0 + pointwise + inv stages 0,1 (pure register).
__device__ __forceinline__ void mid4(float2* x, float cp, float sp) {
  const float c8[8] = { 1.f,  0.92387953f,  0.70710678f,  0.38268343f,
                        0.f, -0.38268343f, -0.70710678f, -0.92387953f };
  const float s8[8] = { 0.f,  0.38268343f,  0.70710678f,  0.92387953f,
                        1.f,  0.92387953f,  0.70710678f,  0.38268343f };
#pragma unroll
  for (int g = 0; g < 8; g += 4) {
    float2 t;
    t.x = x[g].x - x[g+2].x;  t.y = x[g].y - x[g+2].y;
    x[g].x += x[g+2].x;       x[g].y += x[g+2].y;
    x[g+2] = t;
    t.x = x[g+1].x - x[g+3].x; t.y = x[g+1].y - x[g+3].y;
    x[g+1].x += x[g+3].x;      x[g+1].y += x[g+3].y;
    x[g+3] = make_float2(t.y, -t.x);          // * (-i)
  }
#pragma unroll
  for (int g = 0; g < 8; g += 2) {
    float2 t;
    t.x = x[g].x - x[g+1].x; t.y = x[g].y - x[g+1].y;
    x[g].x += x[g+1].x;      x[g].y += x[g+1].y;
    x[g+1] = t;
  }
#pragma unroll
  for (int j = 0; j < 8; ++j) {
    const int rv = ((j & 1) << 2) | (j & 2) | (j >> 2);
    const float sc = (j & 1) ? -(1.f / 2048.f) : (1.f / 2048.f);
    const float fc = (cp * c8[rv] - sp * s8[rv]) * sc;
    const float fs = (sp * c8[rv] + cp * s8[rv]) * sc;
    const float2 a = x[j];
    x[j] = make_float2(a.x * fc - a.y * fs, a.x * fs + a.y * fc);
  }
#pragma unroll
  for (int g = 0; g < 8; g += 2) {
    const float2 t = x[g+1];
    x[g+1].x = x[g].x - t.x; x[g+1].y = x[g].y - t.y;
    x[g].x  += t.x;          x[g].y  += t.y;
  }
#pragma unroll
  for (int g = 0; g < 8; g += 4) {
    float2 t = x[g+2];
    x[g+2].x = x[g].x - t.x; x[g+2].y = x[g].y - t.y;
    x[g].x  += t.x;          x[g].y  += t.y;
    t = make_float2(-x[g+3].y, x[g+3].x);     // * (+i)
    x[g+3].x = x[g+1].x - t.x; x[g+3].y = x[g+1].y - t.y;
    x[g+1].x += t.x;           x[g+1].y += t.y;
  }
}

__global__ __launch_bounds__(256)
void tdi_dual(const float* __restrict__ in_r,
              const float* __restrict__ in_i,
              float4* __restrict__ out,
              int batch) {
  __shared__ __align__(16) float2 As[2][2176];
  __shared__ float sred[2][4][4];             // [fft][wave][S0r,S1r,S0i,S1i]

  const int u = threadIdx.x;                  // 0..255
  const int g = blockIdx.x;
  const int bA = 2 * g;
  const int bB = (2 * g + 1 < batch) ? 2 * g + 1 : 2 * g;

  const float* __restrict__ prA0 = in_r + ((size_t)bA << 12);
  const float* __restrict__ prA1 = prA0 + 2048;
  const float* __restrict__ piA0 = in_i + ((size_t)bA << 12);
  const float* __restrict__ piA1 = piA0 + 2048;
  const float* __restrict__ prB0 = in_r + ((size_t)bB << 12);
  const float* __restrict__ prB1 = prB0 + 2048;
  const float* __restrict__ piB0 = in_i + ((size_t)bB << 12);
  const float* __restrict__ piB1 = piB0 + 2048;

  float2 xA[8], xB[8];
  float s, c;

  // ---- F1: dual load + alternating sums + fwd stages 10,9,8 -------------
  {
    float aAr0 = 0.f, aAr1 = 0.f, aAi0 = 0.f, aAi1 = 0.f;
    float aBr0 = 0.f, aBr1 = 0.f, aBi0 = 0.f, aBi1 = 0.f;
#pragma unroll
    for (int j = 0; j < 8; ++j) {
      const int n = u + 256 * j;
      xA[j] = make_float2(prA0[n], prA1[n]);
      xB[j] = make_float2(prB0[n], prB1[n]);
      aAr0 += xA[j].x;  aAr1 += xA[j].y;
      aBr0 += xB[j].x;  aBr1 += xB[j].y;
      aAi0 += piA0[n];  aAi1 += piA1[n];
      aBi0 += piB0[n];  aBi1 += piB1[n];
    }
    const float sg = (u & 1) ? -1.f : 1.f;    // (-1)^n, n = u + 256j
    aAr0 *= sg; aAr1 *= sg; aAi0 *= sg; aAi1 *= sg;
    aBr0 *= sg; aBr1 *= sg; aBi0 *= sg; aBi1 *= sg;
#pragma unroll
    for (int off = 32; off >= 1; off >>= 1) {
      aAr0 += __shfl_xor(aAr0, off, 64);  aAr1 += __shfl_xor(aAr1, off, 64);
      aAi0 += __shfl_xor(aAi0, off, 64);  aAi1 += __shfl_xor(aAi1, off, 64);
      aBr0 += __shfl_xor(aBr0, off, 64);  aBr1 += __shfl_xor(aBr1, off, 64);
      aBi0 += __shfl_xor(aBi0, off, 64);  aBi1 += __shfl_xor(aBi1, off, 64);
    }
    if ((u & 63) == 0) {
      const int w = u >> 6;
      sred[0][w][0] = aAr0; sred[0][w][1] = aAr1;
      sred[0][w][2] = aAi0; sred[0][w][3] = aAi1;
      sred[1][w][0] = aBr0; sred[1][w][1] = aBr1;
      sred[1][w][2] = aBi0; sred[1][w][3] = aBi1;
    }
    __sincosf((float)u * (PI_F / 1024.f), &s, &c);
    fwd3(xA, c, s);
    fwd3(xB, c, s);
#pragma unroll
    for (int j = 0; j < 8; ++j) {
      As[0][pada(u + 256 * j)] = xA[j];
      As[1][pada(u + 256 * j)] = xB[j];
    }
  }
  __syncthreads();

  // ---- F2: stages 7,6,5 --------------------------------------------------
  {
    const int q = u & 31;
    const int base = ((u >> 5) << 8) | q;
#pragma unroll
    for (int j = 0; j < 8; ++j) {
      xA[j] = As[0][pada(base + 32 * j)];
      xB[j] = As[1][pada(base + 32 * j)];
    }
    __sincosf((float)q * (PI_F / 128.f), &s, &c);
    fwd3(xA, c, s);
    fwd3(xB, c, s);
#pragma unroll
    for (int j = 0; j < 8; ++j) {
      As[0][pada(base + 32 * j)] = xA[j];
      As[1][pada(base + 32 * j)] = xB[j];
    }
  }
  __syncthreads();

  // ---- F3: stages 4,3,2 --------------------------------------------------
  {
    const int q = u & 3;
    const int base = ((u >> 2) << 5) | q;
#pragma unroll
    for (int j = 0; j < 8; ++j) {
      xA[j] = As[0][pada(base + 4 * j)];
      xB[j] = As[1][pada(base + 4 * j)];
    }
    __sincosf((float)q * (PI_F / 16.f), &s, &c);
    fwd3(xA, c, s);
    fwd3(xB, c, s);
#pragma unroll
    for (int j = 0; j < 8; ++j) {
      As[0][pada(base + 4 * j)] = xA[j];
      As[1][pada(base + 4 * j)] = xB[j];
    }
  }
  __syncthreads();

  // ---- F4: fwd 1,0 + pointwise + inv 0,1 (float4 LDS I/O) ----------------
  {
    const int base = u << 3;
#pragma unroll
    for (int k = 0; k < 4; ++k) {
      const float4 a = *(const float4*)&As[0][pada(base + 2 * k)];
      const float4 b = *(const float4*)&As[1][pada(base + 2 * k)];
      xA[2*k]   = make_float2(a.x, a.y);  xA[2*k+1] = make_float2(a.z, a.w);
      xB[2*k]   = make_float2(b.x, b.y);  xB[2*k+1] = make_float2(b.z, b.w);
    }
    float cp, sp;
    __sincosf((float)(__brev((unsigned)u) >> 24) * (PI_F / 2048.f), &sp, &cp);
    mid4(xA, cp, sp);
    mid4(xB, cp, sp);
#pragma unroll
    for (int k = 0; k < 4; ++k) {
      *(float4*)&As[0][pada(base + 2 * k)] =
          make_float4(xA[2*k].x, xA[2*k].y, xA[2*k+1].x, xA[2*k+1].y);
      *(float4*)&As[1][pada(base + 2 * k)] =
          make_float4(xB[2*k].x, xB[2*k].y, xB[2*k+1].x, xB[2*k+1].y);
    }
  }
  __syncthreads();

  // ---- I2: inv stages 2,3,4 ----------------------------------------------
  {
    const int q = u & 3;
    const int base = ((u >> 2) << 5) | q;
#pragma unroll
    for (int j = 0; j < 8; ++j) {
      xA[j] = As[0][pada(base + 4 * j)];
      xB[j] = As[1][pada(base + 4 * j)];
    }
    __sincosf((float)q * (PI_F / 16.f), &s, &c);
    inv3(xA, c, s);
    inv3(xB, c, s);
#pragma unroll
    for (int j = 0; j < 8; ++j) {
      As[0][pada(base + 4 * j)] = xA[j];
      As[1][pada(base + 4 * j)] = xB[j];
    }
  }
  __syncthreads();

  // ---- I3: inv stages 5,6,7 ----------------------------------------------
  {
    const int q = u & 31;
    const int base = ((u >> 5) << 8) | q;
#pragma unroll
    for (int j = 0; j < 8; ++j) {
      xA[j] = As[0][pada(base + 32 * j)];
      xB[j] = As[1][pada(base + 32 * j)];
    }
    __sincosf((float)q * (PI_F / 128.f), &s, &c);
    inv3(xA, c, s);
    inv3(xB, c, s);
#pragma unroll
    for (int j = 0; j < 8; ++j) {
      As[0][pada(base + 32 * j)] = xA[j];
      As[1][pada(base + 32 * j)] = xB[j];
    }
  }
  __syncthreads();

  // ---- I4: inv stages 8,9,10 ---------------------------------------------
  {
#pragma unroll
    for (int j = 0; j < 8; ++j) {
      xA[j] = As[0][pada(u + 256 * j)];
      xB[j] = As[1][pada(u + 256 * j)];
    }
    __sincosf((float)u * (PI_F / 1024.f), &s, &c);
    inv3(xA, c, s);
    inv3(xB, c, s);
#pragma unroll
    for (int j = 0; j < 8; ++j) {
      As[0][pada(u + 256 * j)] = xA[j];
      As[1][pada(u + 256 * j)] = xB[j];
    }
  }
  __syncthreads();

  // ---- Epilogue: Nyquist corrections + lerp + float4 stores, both batches
#pragma unroll
  for (int f = 0; f < 2; ++f) {
    const int b = (f == 0) ? bA : bB;
    const float S0r = sred[f][0][0] + sred[f][1][0] + sred[f][2][0] + sred[f][3][0];
    const float S1r = sred[f][0][1] + sred[f][1][1] + sred[f][2][1] + sred[f][3][1];
    const float S0i = sred[f][0][2] + sred[f][1][2] + sred[f][2][2] + sred[f][3][2];
    const float S1i = sred[f][0][3] + sred[f][1][3] + sred[f][2][3] + sred[f][3][3];
    const float alpha = (S0i - S1r) * (1.f / 2048.f);
    const float beta  = (S0r + S1i) * (1.f / 2048.f);

    const float* __restrict__ p0 = in_r + ((size_t)b << 12);
    const float* __restrict__ p1 = p0 + 2048;
    float4* __restrict__ orow = out + (size_t)b * (14 * 1024);
#pragma unroll
    for (int e = 0; e < 4; ++e) {
      const int q = u + (e << 8);
      const float2 E0 = *(const float2*)&p0[2 * q];
      const float2 E1 = *(const float2*)&p1[2 * q];
      const float4 a  = *(const float4*)&As[f][pada(2 * q)];
      const float2 O0 = make_float2(a.x + alpha, a.z - alpha);
      const float2 O1 = make_float2(a.y + beta,  a.w - beta);
#pragma unroll
      for (int t = 0; t < 14; ++t) {
        const float wt = (t < 2) ? 0.f : (t >= 11) ? 1.f : (float)(t - 2) * (1.f / 9.f);
        float4 v;
        v.x = E0.x + wt * (E1.x - E0.x);
        v.y = O0.x + wt * (O1.x - O0.x);
        v.z = E0.y + wt * (E1.y - E0.y);
        v.w = O0.y + wt * (O1.y - O0.y);
        orow[t * 1024 + q] = v;
      }
    }
  }
}

extern "C" void kernel_launch(void* const* d_in, const int* in_sizes, int n_in,
                              void* d_out, int out_size, void* d_ws, size_t ws_size,
                              hipStream_t stream) {
  const float* hr = (const float*)d_in[0];
  const float* hi = (const float*)d_in[1];
  const int batch = in_sizes[0] / NSC;          // 512 for the reference config
  const int nblk = (batch + 1) / 2;             // 256
  tdi_dual<<<dim3(nblk), dim3(256), 0, stream>>>(hr, hi, (float4*)d_out, batch);
}